// Round 3
// baseline (651.450 us; speedup 1.0000x reference)
//
#include <hip/hip_runtime.h>
#include <hip/hip_bf16.h>
#include <math.h>

// ---------- dims ----------
#define BATCH 17
#define T_EX 16
#define H0 383
#define W0 287
#define C1 64
#define H1 95
#define W1 71
#define H1P 47
#define W1P 35
#define C2 192
#define H2P 23
#define W2P 17
#define C3 384
#define C45 256
#define H5P 11
#define W5P 8
#define DD 256
#define MM 88
#define TM 1408

#define HP1 389
#define WP1 292

typedef unsigned short ushort_t;
typedef __attribute__((ext_vector_type(8))) short short8;
typedef __attribute__((ext_vector_type(4))) float f32x4;

__device__ __forceinline__ float lrelu(float v) { return v > 0.f ? v : 0.01f * v; }

__device__ __forceinline__ ushort_t f2bf(float f) {
    unsigned int u = __float_as_uint(f);
    unsigned int r = (u + 0x7fffu + ((u >> 16) & 1u)) >> 16;
    return (ushort_t)r;
}
__device__ __forceinline__ float b2f(ushort_t b) {
    return __uint_as_float(((unsigned int)b) << 16);
}
__device__ __forceinline__ short8 ld16(const ushort_t* p) { return *(const short8*)p; }

// ---------- zero fill ----------
__global__ void zfill_k(float4* __restrict__ p, int n4) {
    int idx = blockIdx.x * 256 + threadIdx.x;
    if (idx < n4) p[idx] = (float4){0.f, 0.f, 0.f, 0.f};
}

// ---------- conv1 input prep: fp32 NCHW -> bf16 NHWC padded (C=4, pad 2) ----------
__global__ void prep1_k(const float* __restrict__ search, const float* __restrict__ exemp,
                        ushort_t* __restrict__ out) {
    int idx = blockIdx.x * 256 + threadIdx.x;
    if (idx >= BATCH * H0 * W0) return;
    int ix = idx % W0; int t = idx / W0;
    int iy = t % H0; int b = t / H0;
    const float* src = (b == 0) ? search : exemp + (size_t)(b - 1) * 3 * H0 * W0;
    const int hw = H0 * W0;
    float v0 = src[iy * W0 + ix];
    float v1 = src[hw + iy * W0 + ix];
    float v2 = src[2 * hw + iy * W0 + ix];
    ushort4 o;
    o.x = f2bf(v0); o.y = f2bf(v1); o.z = f2bf(v2); o.w = 0;
    *(ushort4*)&out[(((size_t)b * HP1 + iy + 2) * WP1 + ix + 2) * 4] = o;
}

// ---------- conv weight prep: OIHW fp32 -> bf16 MFMA tiles, K-order (ky,kx,ic) ----------
__global__ void wprep_k(const float* __restrict__ w, ushort_t* __restrict__ out,
                        int KH, int KWl, int KWr, int CINl, int CINr,
                        int NKS, int nch) {
    int idx = blockIdx.x * 256 + threadIdx.x;
    if (idx >= nch) return;
    int c = idx & 255;
    int rest = idx >> 8;
    int ks = rest % NKS;
    int ocb = rest / NKS;
    int k8 = c >> 6, m = c & 63;
    int oc = ocb * 64 + m;
    int KWC = KWl * CINl;
    ushort_t* o = out + (size_t)idx * 8;
#pragma unroll
    for (int j = 0; j < 8; ++j) {
        int kg = ks * 32 + k8 * 8 + j;
        int ky = kg / KWC; int rem = kg - ky * KWC;
        int kx = rem / CINl; int ic = rem - kx * CINl;
        float v = 0.f;
        if (ky < KH && kx < KWr && ic < CINr)
            v = w[(((size_t)oc * CINr + ic) * KH + ky) * KWr + kx];
        o[j] = f2bf(v);
    }
}

// ---------- fused gemm weight prep (ws1 | ws2 | wcd), tiled layout ----------
__global__ void wprep_gemm_k(const float* __restrict__ ws1, const float* __restrict__ ws2,
                             const float* __restrict__ wcd, ushort_t* __restrict__ WS1T,
                             ushort_t* __restrict__ WS2T, ushort_t* __restrict__ WCDT) {
    int idx = blockIdx.x * 256 + threadIdx.x;
    const float* src; ushort_t* dst; int NKS, mode = 0, sa = 1, sk = 0, base;
    if (idx < 16384)       { src = ws1; dst = WS1T; NKS = 8;  sk = 512; base = idx; }
    else if (idx < 32768)  { src = ws2; dst = WS2T; NKS = 16; sk = 256; base = idx - 16384; }
    else if (idx < 57344)  { src = wcd; dst = WCDT; NKS = 24; mode = 1; base = idx - 32768; }
    else return;
    int c = base & 255;
    int rest = base >> 8;
    int ks = rest % NKS;
    int ocb = rest / NKS;
    int k8 = c >> 6, m = c & 63;
    int oc = ocb * 64 + m;
    ushort_t* o = dst + (size_t)base * 8;
#pragma unroll
    for (int j = 0; j < 8; ++j) {
        int kg = ks * 32 + k8 * 8 + j;
        float v;
        if (mode == 0) v = src[(size_t)oc * sa + (size_t)kg * sk];
        else           v = src[(size_t)oc * 768 + (kg & 255) * 3 + (kg >> 8)];
        o[j] = f2bf(v);
    }
}

// ====================================================================
// bf16 MFMA implicit-GEMM conv, v8: ZERO-LDS, ZERO-BARRIER direct path.
//  - B-fragments (8 consecutive K-elems = 16B, verified 16B-aligned for
//    all 5 convs) loaded straight from global NHWC into MFMA operands;
//    A from pre-tiled weights (L2-resident). No LDS staging, no
//    s_barrier in the main loop -> waves free-run, latency hidden by
//    TLP (conv1/2: >=10 waves/CU, VGPR capped via launch_bounds) or by
//    explicit ping-pong prefetch ILP (conv3-5, PREFB, low grid).
//  - wave = 32oc x 64px, BK=64/step: 16 MFMA vs 12 VMEM loads/step.
//  - block = 4 waves = 64oc x 128px (wr: oc-half, wc: px-half).
//  - Only LDS: 1.7 KB offs table (one barrier at init).
// ====================================================================
__device__ __forceinline__ void conv_ld(short8 (&A)[2][2], short8 (&B)[2][4],
                                        const ushort_t* wblk,
                                        const ushort_t* const (&bp)[4],
                                        const int* offs, int ks, int quad) {
    const ushort_t* wk = wblk + (size_t)ks * 4096;
    A[0][0] = ld16(wk);
    A[0][1] = ld16(wk + 128);
    A[1][0] = ld16(wk + 2048);
    A[1][1] = ld16(wk + 2176);
    const int g = ks * 8 + quad;
    const int o0 = offs[g], o1 = offs[g + 4];
#pragma unroll
    for (int cn = 0; cn < 4; ++cn) {
        B[0][cn] = ld16(bp[cn] + o0);
        B[1][cn] = ld16(bp[cn] + o1);
    }
}

__device__ __forceinline__ void conv_mm(f32x4 (&acc)[2][4], const short8 (&A)[2][2],
                                        const short8 (&B)[2][4]) {
#pragma unroll
    for (int h = 0; h < 2; ++h)
#pragma unroll
        for (int cn = 0; cn < 4; ++cn) {
            acc[0][cn] = __builtin_amdgcn_mfma_f32_16x16x32_bf16(A[h][0], B[h][cn], acc[0][cn], 0, 0, 0);
            acc[1][cn] = __builtin_amdgcn_mfma_f32_16x16x32_bf16(A[h][1], B[h][cn], acc[1][cn], 0, 0, 0);
        }
}

template <int STRIDE, bool PREFB, int MINW>
__global__ __launch_bounds__(256, MINW) void conv_mfma8(
    const ushort_t* __restrict__ inp, const ushort_t* __restrict__ wt,
    const float* __restrict__ bias, ushort_t* __restrict__ out,
    int Hp, int Wp, int C, int Wout, int HW, int Ntot, int NKS2, int KWl,
    int OHp, int OWp, int OPAD, int COUT) {
    const int tid = threadIdx.x;
    const int wv = tid >> 6, lane = tid & 63;
    const int quad = lane >> 4, l16 = lane & 15;
    const int wr = wv >> 1, wc = wv & 1;     // 2x2 wave grid: oc-half x px-half
    const int n_blk = blockIdx.x * 128;
    const int ocb = blockIdx.y;

    __shared__ int offs[432];
    const int KWC = KWl * C;
    for (int g = tid; g < NKS2 * 8; g += 256) {
        int kg = g * 8;
        int ky = kg / KWC; int rem = kg - ky * KWC;
        int kx = rem / C; int c8 = rem - kx * C;
        offs[g] = (ky * Wp + kx) * C + c8;
    }
    __syncthreads();   // the ONLY barrier

    // per-lane pixel base pointers for the 4 px-fragments (batch-flattened)
    const ushort_t* bp[4];
#pragma unroll
    for (int cn = 0; cn < 4; ++cn) {
        int n = n_blk + wc * 64 + cn * 16 + l16;
        if (n >= Ntot) n = Ntot - 1;
        int b = n / HW, p = n - b * HW;
        int oy = p / Wout, ox = p - oy * Wout;
        bp[cn] = inp + (size_t)b * Hp * Wp * C +
                 (size_t)(oy * STRIDE * Wp + ox * STRIDE) * C;
    }

    f32x4 acc[2][4];
#pragma unroll
    for (int m = 0; m < 2; ++m)
#pragma unroll
        for (int cn = 0; cn < 4; ++cn) acc[m][cn] = (f32x4){0.f, 0.f, 0.f, 0.f};

    // A base: pre-tiled [ocb][ks32:2][k8=quad][oc m][8]; m = wr*32 + am*16 + l16
    const ushort_t* wblk = wt + (size_t)ocb * (size_t)NKS2 * 4096 +
                           (size_t)(quad * 64 + wr * 32 + l16) * 8;

    if constexpr (!PREFB) {
        // plain loop: loads at step top, 16 MFMAs; latency hidden by TLP
        for (int ks = 0; ks < NKS2; ++ks) {
            short8 A[2][2], B[2][4];
            conv_ld(A, B, wblk, bp, offs, ks, quad);
            conv_mm(acc, A, B);
        }
    } else {
        // ping-pong unroll-by-2: load buf B for step k+1 while computing buf A
        short8 aA[2][2], bA[2][4], aB[2][2], bB[2][4];
        conv_ld(aA, bA, wblk, bp, offs, 0, quad);
        int ks = 0;
        for (; ks + 2 <= NKS2; ks += 2) {
            if (ks + 1 < NKS2) conv_ld(aB, bB, wblk, bp, offs, ks + 1, quad);
            conv_mm(acc, aA, bA);
            if (ks + 2 < NKS2) conv_ld(aA, bA, wblk, bp, offs, ks + 2, quad);
            conv_mm(acc, aB, bB);
        }
        if (ks < NKS2) conv_mm(acc, aA, bA);   // odd-NKS2 tail
    }

    const int oc0 = ocb * 64 + wr * 32 + quad * 4;
#pragma unroll
    for (int cn = 0; cn < 4; ++cn) {
        int n = n_blk + wc * 64 + cn * 16 + l16;
        if (n < Ntot) {
            int bb = n / HW; int pix = n - bb * HW;
            int y = pix / Wout, x = pix - y * Wout;
            size_t base = (((size_t)bb * OHp + y + OPAD) * OWp + x + OPAD) * COUT;
#pragma unroll
            for (int am = 0; am < 2; ++am) {
                const int oc = oc0 + am * 16;
                ushort4 o;
                o.x = f2bf(fmaxf(acc[am][cn][0] + bias[oc], 0.f));
                o.y = f2bf(fmaxf(acc[am][cn][1] + bias[oc + 1], 0.f));
                o.z = f2bf(fmaxf(acc[am][cn][2] + bias[oc + 2], 0.f));
                o.w = f2bf(fmaxf(acc[am][cn][3] + bias[oc + 3], 0.f));
                *(ushort4*)&out[base + oc] = o;
            }
        }
    }
}

// ====================================================================
// Generic bf16 MFMA GEMM: A direct from global (tiled), B LDS dbuf.
// ====================================================================
template <int MODE, bool HASBIAS, bool SC1>
__global__ __launch_bounds__(256) void gemm_mfma3(
    const ushort_t* __restrict__ Bsrc, const ushort_t* __restrict__ wt,
    const float* __restrict__ bias, float* __restrict__ out,
    int RS, int N, int NKS, int sn, int sc) {
    const int tid = threadIdx.x;
    const int wv = tid >> 6, lane = tid & 63;
    const int quad = lane >> 4, l16 = lane & 15;
    const int n_blk = blockIdx.x * 64;
    const int ocb = blockIdx.y;

    __shared__ ushort_t Bs[2][2048];

    int n_g = n_blk + lane;
    int n_gc = n_g < N ? n_g : N - 1;
    int row = (MODE == 1) ? (1 + (n_gc & 15)) * MM + (n_gc >> 4) : n_gc;
    const size_t base0 = (size_t)row * RS;

    f32x4 acc[4];
#pragma unroll
    for (int cn = 0; cn < 4; ++cn) acc[cn] = (f32x4){0.f, 0.f, 0.f, 0.f};

    const ushort_t* wblk = wt + (size_t)ocb * NKS * 2048;
    const int afrag = (quad * 64 + wv * 16 + l16) * 8;

    short8 a0 = ld16(wblk + afrag);
    *(short8*)&Bs[0][tid * 8] = ld16(Bsrc + base0 + wv * 8);
    __syncthreads();

    for (int ks = 0; ks < NKS; ++ks) {
        const int cur = ks & 1, nxt = cur ^ 1;
        short8 a1, bn;
        const bool more = (ks + 1 < NKS);
        if (more) {
            a1 = ld16(wblk + (ks + 1) * 2048 + afrag);
            bn = ld16(Bsrc + base0 + (ks + 1) * 32 + wv * 8);
        }
#pragma unroll
        for (int cn = 0; cn < 4; ++cn) {
            const short8 bfr = *(const short8*)&Bs[cur][(quad * 64 + cn * 16 + l16) * 8];
            acc[cn] = __builtin_amdgcn_mfma_f32_16x16x32_bf16(a0, bfr, acc[cn], 0, 0, 0);
        }
        if (more) *(short8*)&Bs[nxt][tid * 8] = bn;
        a0 = a1;
        __syncthreads();
    }

    const int oc0 = ocb * 64 + wv * 16 + quad * 4;
    float bb[4] = {0.f, 0.f, 0.f, 0.f};
    if (HASBIAS) { bb[0] = bias[oc0]; bb[1] = bias[oc0+1]; bb[2] = bias[oc0+2]; bb[3] = bias[oc0+3]; }
#pragma unroll
    for (int cn = 0; cn < 4; ++cn) {
        int n = n_blk + cn * 16 + l16;
        if (n < N) {
            if (SC1) {
                float4 o;
                o.x = acc[cn][0] + bb[0]; o.y = acc[cn][1] + bb[1];
                o.z = acc[cn][2] + bb[2]; o.w = acc[cn][3] + bb[3];
                *(float4*)&out[(size_t)n * sn + oc0] = o;
            } else {
#pragma unroll
                for (int reg = 0; reg < 4; ++reg)
                    out[(size_t)n * sn + (size_t)(oc0 + reg) * sc] = acc[cn][reg] + bb[reg];
            }
        }
    }
}

// ---------- maxpool k3 s2 VALID, NHWC bf16 ----------
__global__ void pool_nhwc(const ushort_t* __restrict__ in, ushort_t* __restrict__ out,
                          int C, int Hin, int Win, int Hout, int Wout,
                          int OHp, int OWp, int OPAD) {
    int total = BATCH * C * Hout * Wout;
    int idx = blockIdx.x * 256 + threadIdx.x;
    if (idx >= total) return;
    int c = idx % C; int r = idx / C;
    int x = r % Wout; r /= Wout;
    int y = r % Hout; int b = r / Hout;
    const int rs = Win * C;
    const ushort_t* p = in + (((size_t)b * Hin + 2 * y) * Win + 2 * x) * C + c;
    float m = b2f(p[0]);
    m = fmaxf(m, b2f(p[C])); m = fmaxf(m, b2f(p[2 * C]));
    m = fmaxf(m, b2f(p[rs])); m = fmaxf(m, b2f(p[rs + C])); m = fmaxf(m, b2f(p[rs + 2 * C]));
    m = fmaxf(m, b2f(p[2 * rs])); m = fmaxf(m, b2f(p[2 * rs + C])); m = fmaxf(m, b2f(p[2 * rs + 2 * C]));
    out[(((size_t)b * OHp + y + OPAD) * OWp + x + OPAD) * C + c] = f2bf(m);
}

// ---------- pool5: NHWC bf16 -> P fp32 [b][m][d] + PB bf16 + XfPad ----------
__global__ void pool5_k(const ushort_t* __restrict__ in, float* __restrict__ P,
                        ushort_t* __restrict__ PB, ushort_t* __restrict__ XfPad) {
    int total = BATCH * 256 * MM;
    int idx = blockIdx.x * 256 + threadIdx.x;
    if (idx >= total) return;
    int c = idx % 256; int r = idx / 256;
    int x = r % W5P; r /= W5P;
    int y = r % H5P; int b = r / H5P;
    const int rs = W2P * 256;
    const ushort_t* p = in + (((size_t)b * H2P + 2 * y) * W2P + 2 * x) * 256 + c;
    float m = b2f(p[0]);
    m = fmaxf(m, b2f(p[256])); m = fmaxf(m, b2f(p[512]));
    m = fmaxf(m, b2f(p[rs])); m = fmaxf(m, b2f(p[rs + 256])); m = fmaxf(m, b2f(p[rs + 512]));
    m = fmaxf(m, b2f(p[2 * rs])); m = fmaxf(m, b2f(p[2 * rs + 256])); m = fmaxf(m, b2f(p[2 * rs + 512]));
    int mm = y * W5P + x;
    size_t o = ((size_t)b * MM + mm) * 256 + c;
    P[o] = m;
    ushort_t mb = f2bf(m);
    PB[o] = mb;
    if (b == 0) XfPad[(size_t)(mm + 1) * 256 + c] = mb;
}

// ---------- v[c] = max_m xc[c*88+m] ----------
__global__ void vmax_k(const float* __restrict__ xc, float* __restrict__ v) {
    int c = blockIdx.x * 64 + threadIdx.x;
    float m = -INFINITY;
    for (int j = 0; j < MM; ++j) m = fmaxf(m, xc[(size_t)c * MM + j]);
    v[c] = m;
}

__global__ void xhat_k(const float* __restrict__ v, const float* __restrict__ wt,
                       const float* __restrict__ bt, float* __restrict__ xhat) {
    __shared__ float lv[256];
    for (int j = threadIdx.x; j < 256; j += 256) lv[j] = v[j];
    __syncthreads();
    int idx = blockIdx.x * 256 + threadIdx.x;
    if (idx >= DD * MM) return;
    int k = idx % MM, o = idx / MM;
    float acc = bt[o];
    for (int i = 0; i < 256; ++i) acc = fmaf(lv[i], wt[(i * 256 + o) * MM + k], acc);
    xhat[idx] = acc;
}

__global__ void s1_k(const float* __restrict__ Y1, float* __restrict__ S1) {
    int idx = blockIdx.x * 256 + threadIdx.x;
    if (idx >= T_EX * 512) return;
    int c = idx % 512, t = idx / 512;
    float acc = 0.f;
    for (int m = 0; m < MM; ++m) acc += Y1[(m * T_EX + t) * 512 + c];
    S1[idx] = acc;
}

__global__ void h1_k(const float* __restrict__ Y1, const float* __restrict__ S1,
                     const float* __restrict__ bs1, ushort_t* __restrict__ h1b) {
    int idx = blockIdx.x * 256 + threadIdx.x;
    if (idx >= TM * 512) return;
    int c = idx % 512; int n = idx / 512;
    int t = n % T_EX;
    float val = S1[t * 512 + c] + bs1[c];
    if (t == 0) val -= Y1[idx];
    h1b[idx] = f2bf(lrelu(val));
}

__global__ void s2_k(const float* __restrict__ Y2, float* __restrict__ S2) {
    int idx = blockIdx.x * 256 + threadIdx.x;
    if (idx >= T_EX * 256) return;
    int c = idx % 256, t = idx / 256;
    float acc = 0.f;
    for (int m = 0; m < MM; ++m) acc += Y2[(m * T_EX + t) * 256 + c];
    S2[idx] = acc;
}

__global__ void h2_k(const float* __restrict__ Y2, const float* __restrict__ S2,
                     const float* __restrict__ bs2, float* __restrict__ h2) {
    int idx = blockIdx.x * 256 + threadIdx.x;
    if (idx >= TM * 256) return;
    int c = idx % 256; int n = idx / 256;
    int t = n % T_EX;
    float val = S2[t * 256 + c] + bs2[c];
    if (t == 0) val -= Y2[idx];
    h2[idx] = lrelu(val);
}

__global__ void v1vx_k(const float* __restrict__ h2, const float* __restrict__ xhat,
                       float* __restrict__ V1, float* __restrict__ Vx) {
    int idx = blockIdx.x * 256 + threadIdx.x;
    if (idx >= DD * MM) return;
    int m = idx % MM, d = idx / MM;
    float mx = -INFINITY;
    for (int t = 0; t < T_EX; ++t) mx = fmaxf(mx, h2[(m * T_EX + t) * 256 + d]);
    V1[idx] = mx;
    Vx[idx] = mx + xhat[idx];
}

__global__ void lin88_k(const float* __restrict__ Wg, const float* __restrict__ bg,
                        const float* __restrict__ Wh, const float* __restrict__ bh,
                        const float* __restrict__ Vin, float* __restrict__ Gout,
                        float* __restrict__ Hout) {
    int idx = blockIdx.x * 256 + threadIdx.x;
    if (idx >= DD * MM) return;
    const float* W = blockIdx.y ? Wh : Wg;
    const float* bias = blockIdx.y ? bh : bg;
    float* out = blockIdx.y ? Hout : Gout;
    int m = idx % MM, o = idx / MM;
    const float* wr = W + o * 256;
    float acc = bias[o];
    for (int i = 0; i < 256; ++i) acc = fmaf(wr[i], Vin[i * MM + m], acc);
    out[idx] = acc;
}

// ---------- fused Smat row + softmax ----------
__global__ void smsm_k(const float* __restrict__ Hh, const float* __restrict__ G,
                       float* __restrict__ A2) {
    int j = blockIdx.x;
    int tid = threadIdx.x;   // 128
    __shared__ float row[96];
    __shared__ float red[128];
    for (int i = tid; i < MM; i += 128) {
        float acc = 0.f;
        for (int c = 0; c < 256; ++c) acc = fmaf(Hh[c * MM + j], G[c * MM + i], acc);
        row[i] = acc;
    }
    __syncthreads();
    float val = (tid < MM) ? row[tid] : -INFINITY;
    red[tid] = val; __syncthreads();
    for (int s = 64; s > 0; s >>= 1) {
        if (tid < s) red[tid] = fmaxf(red[tid], red[tid + s]);
        __syncthreads();
    }
    float mx = red[0]; __syncthreads();
    float e = (tid < MM) ? expf(val - mx) : 0.f;
    red[tid] = e; __syncthreads();
    for (int s = 64; s > 0; s >>= 1) {
        if (tid < s) red[tid] += red[tid + s];
        __syncthreads();
    }
    float inv = 1.f / red[0];
    if (tid < MM) A2[j * MM + tid] = e * inv;
}

__global__ void t1_k(const float* __restrict__ V1, const float* __restrict__ wc1,
                     float* __restrict__ t1) {
    int idx = blockIdx.x * 256 + threadIdx.x;
    if (idx >= MM * 384) return;
    int c = idx % 384, m = idx / 384;
    float acc = 0.f;
    for (int d = 0; d < 256; ++d) acc = fmaf(V1[d * MM + m], wc1[d * 384 + c], acc);
    t1[idx] = acc;
}

__global__ void c1_k(const float* __restrict__ A2, const float* __restrict__ t1,
                     const float* __restrict__ bc1, float* __restrict__ c1) {
    int idx = blockIdx.x * 256 + threadIdx.x;
    if (idx >= MM * 384) return;
    int c = idx % 384, j = idx / 384;
    float acc = bc1[c];
    for (int i = 0; i < MM; ++i) acc = fmaf(A2[j * MM + i], t1[i * 384 + c], acc);
    c1[idx] = lrelu(acc);
}

__global__ void t2_k(const float* __restrict__ c1, const float* __restrict__ wc2,
                     float* __restrict__ t2) {
    int idx = blockIdx.x * 256 + threadIdx.x;
    if (idx >= MM * 256) return;
    int c = idx % 256, m = idx / 256;
    const float* cr = c1 + m * 384;
    float acc = 0.f;
    for (int d = 0; d < 384; ++d) acc = fmaf(cr[d], wc2[d * 256 + c], acc);
    t2[idx] = acc;
}

__global__ void v2_k(const float* __restrict__ A2, const float* __restrict__ t2,
                     const float* __restrict__ bc2, float* __restrict__ V2m) {
    int idx = blockIdx.x * 256 + threadIdx.x;
    if (idx >= MM * 256) return;
    int c = idx % 256, j = idx / 256;
    float acc = bc2[c];
    for (int i = 0; i < MM; ++i) acc = fmaf(A2[j * MM + i], t2[i * 256 + c], acc);
    V2m[idx] = lrelu(acc);
}

__global__ void final_k(const float* __restrict__ Xf2, const float* __restrict__ V2m,
                        float* __restrict__ out) {
    __shared__ float red[256];
    float acc = 0.f;
    for (int idx = threadIdx.x; idx < DD * MM; idx += 256)
        acc = fmaf(Xf2[idx], V2m[idx], acc);
    red[threadIdx.x] = acc; __syncthreads();
    for (int s = 128; s > 0; s >>= 1) {
        if (threadIdx.x < s) red[threadIdx.x] += red[threadIdx.x + s];
        __syncthreads();
    }
    if (threadIdx.x == 0) out[0] = red[0];
}

extern "C" void kernel_launch(void* const* d_in, const int* in_sizes, int n_in,
                              void* d_out, int out_size, void* d_ws, size_t ws_size,
                              hipStream_t stream) {
    const float* search = (const float*)d_in[0];
    const float* exemp  = (const float*)d_in[1];
    const float* aw1 = (const float*)d_in[2];  const float* ab1 = (const float*)d_in[3];
    const float* aw2 = (const float*)d_in[4];  const float* ab2 = (const float*)d_in[5];
    const float* aw3 = (const float*)d_in[6];  const float* ab3 = (const float*)d_in[7];
    const float* aw4 = (const float*)d_in[8];  const float* ab4 = (const float*)d_in[9];
    const float* aw5 = (const float*)d_in[10]; const float* ab5 = (const float*)d_in[11];
    const float* wcd = (const float*)d_in[12]; const float* bcd = (const float*)d_in[13];
    const float* wt  = (const float*)d_in[14]; const float* bt  = (const float*)d_in[15];
    const float* ws1 = (const float*)d_in[16]; const float* bs1 = (const float*)d_in[17];
    const float* ws2 = (const float*)d_in[18]; const float* bs2 = (const float*)d_in[19];
    const float* wg  = (const float*)d_in[20]; const float* bg  = (const float*)d_in[21];
    const float* wh  = (const float*)d_in[22]; const float* bh  = (const float*)d_in[23];
    const float* wc1 = (const float*)d_in[24]; const float* bc1 = (const float*)d_in[25];
    const float* wc2 = (const float*)d_in[26]; const float* bc2 = (const float*)d_in[27];

    float* ws = (float*)d_ws;
    float* R1 = ws;
    float* R2 = ws + 3870720;
    float* R3 = ws + 7544832;
    float* Wg = ws + 8628864;

    ushort_t* in1p  = (ushort_t*)R1;
    ushort_t* c1out = (ushort_t*)R2;
    ushort_t* p1out = (ushort_t*)R3;
    ushort_t* c2out = (ushort_t*)R1;
    ushort_t* p2out = (ushort_t*)R2;
    ushort_t* c3out = (ushort_t*)(R2 + 775200);
    ushort_t* c4out = (ushort_t*)R1;
    ushort_t* c5out = (ushort_t*)R3;
    ushort_t* WT    = (ushort_t*)Wg;

    // ---- conv stack (tiled weights; batch-flattened N; 64oc x 128px blocks) ----
    zfill_k<<<(965500 + 255) / 256, 256, 0, stream>>>((float4*)R1, 965500);
    prep1_k<<<(BATCH * H0 * W0 + 255) / 256, 256, 0, stream>>>(search, exemp, in1p);
    wprep_k<<<(4608 + 255) / 256, 256, 0, stream>>>(aw1, WT, 11, 12, 11, 4, 3, 18, 4608);
    conv_mfma8<4, false, 4><<<dim3(896, 1), 256, 0, stream>>>(
        in1p, WT, ab1, c1out, HP1, WP1, 4, W1, H1 * W1, BATCH * H1 * W1, 9, 12, H1, W1, 0, 64);
    zfill_k<<<(270504 + 255) / 256, 256, 0, stream>>>((float4*)R3, 270504);
    pool_nhwc<<<(BATCH * 64 * H1P * W1P + 255) / 256, 256, 0, stream>>>(
        c1out, p1out, 64, H1, W1, H1P, W1P, 51, 39, 2);
    wprep_k<<<(38400 + 255) / 256, 256, 0, stream>>>(aw2, WT, 5, 5, 5, 64, 64, 50, 38400);
    conv_mfma8<1, false, 4><<<dim3(219, 3), 256, 0, stream>>>(
        p1out, WT, ab2, c2out, 51, 39, 64, W1P, H1P * W1P, BATCH * H1P * W1P, 25, 5, H1P, W1P, 0, 192);
    zfill_k<<<(581400 + 255) / 256, 256, 0, stream>>>((float4*)R2, 581400);
    pool_nhwc<<<(BATCH * 192 * H2P * W2P + 255) / 256, 256, 0, stream>>>(
        c2out, p2out, 192, H1P, W1P, H2P, W2P, 25, 19, 1);
    wprep_k<<<(82944 + 255) / 256, 256, 0, stream>>>(aw3, WT, 3, 3, 3, 192, 192, 54, 82944);
    conv_mfma8<1, true, 2><<<dim3(52, 6), 256, 0, stream>>>(
        p2out, WT, ab3, c3out, 25, 19, 192, W2P, H2P * W2P, BATCH * H2P * W2P, 27, 3, 25, 19, 1, 384);
    zfill_k<<<(258400 + 255) / 256, 256, 0, stream>>>((float4*)R1, 258400);
    wprep_k<<<(110592 + 255) / 256, 256, 0, stream>>>(aw4, WT, 3, 3, 3, 384, 384, 108, 110592);
    conv_mfma8<1, true, 2><<<dim3(52, 4), 256, 0, stream>>>(
        c3out, WT, ab4, c4out, 25, 19, 384, W2P, H2P * W2P, BATCH * H2P * W2P, 54, 3, 25, 19, 1, 256);
    wprep_k<<<(73728 + 255) / 256, 256, 0, stream>>>(aw5, WT, 3, 3, 3, 256, 256, 72, 73728);
    conv_mfma8<1, true, 2><<<dim3(52, 4), 256, 0, stream>>>(
        c4out, WT, ab5, c5out, 25, 19, 256, W2P, H2P * W2P, BATCH * H2P * W2P, 36, 3, H2P, W2P, 0, 256);

    // ---- tail region layout in R1 ----
    float*    P      = R1 + 2417664;
    ushort_t* PB     = (ushort_t*)(R1 + 2800640);
    ushort_t* XfPad  = (ushort_t*)(R1 + 2992128);   // rows 0 & 89 zeroed by first R1 zfill
    float*    xc     = R1 + 3003648;

    ushort_t* WS1T = (ushort_t*)Wg;
    ushort_t* WS2T = (ushort_t*)(Wg + 65536);
    ushort_t* WCDT = (ushort_t*)(Wg + 131072);
    wprep_gemm_k<<<(57344 + 255) / 256, 256, 0, stream>>>(ws1, ws2, wcd, WS1T, WS2T, WCDT);

    pool5_k<<<(BATCH * 256 * MM + 255) / 256, 256, 0, stream>>>(c5out, P, PB, XfPad);
    float* Xf2 = P;

    float* v_   = R1 + 0;
    float* xhat = R1 + 1024;
    float* Y1   = R1 + 23552;
    float* S1   = R1 + 744448;
    ushort_t* h1b = (ushort_t*)(R1 + 752640);
    float* Y2   = R1 + 1473536;
    float* S2   = R1 + 1833984;
    float* h2   = R1 + 1838080;
    float* V1   = R1 + 2198528;
    float* Vx   = R1 + 2221056;
    float* G    = R1 + 2243584;
    float* Hh   = R1 + 2266112;
    float* A2   = R1 + 2296832;
    float* t1   = R1 + 2305024;
    float* c1   = R1 + 2338816;
    float* t2   = R1 + 2372608;
    float* V2m  = R1 + 2395136;

    gemm_mfma3<0, true, false><<<dim3(2, 4), 256, 0, stream>>>(
        XfPad, WCDT, bcd, xc, 256, MM, 24, 1, MM);
    vmax_k<<<4, 64, 0, stream>>>(xc, v_);
    xhat_k<<<(DD * MM + 255) / 256, 256, 0, stream>>>(v_, wt, bt, xhat);

    gemm_mfma3<1, false, true><<<dim3(22, 8), 256, 0, stream>>>(
        PB, WS1T, nullptr, Y1, 256, TM, 8, 512, 1);
    s1_k<<<(T_EX * 512 + 255) / 256, 256, 0, stream>>>(Y1, S1);
    h1_k<<<(TM * 512 + 255) / 256, 256, 0, stream>>>(Y1, S1, bs1, h1b);
    gemm_mfma3<0, false, true><<<dim3(22, 4), 256, 0, stream>>>(
        h1b, WS2T, nullptr, Y2, 512, TM, 16, 256, 1);
    s2_k<<<(T_EX * 256 + 255) / 256, 256, 0, stream>>>(Y2, S2);
    h2_k<<<(TM * 256 + 255) / 256, 256, 0, stream>>>(Y2, S2, bs2, h2);
    v1vx_k<<<(DD * MM + 255) / 256, 256, 0, stream>>>(h2, xhat, V1, Vx);

    lin88_k<<<dim3((DD * MM + 255) / 256, 2), 256, 0, stream>>>(wg, bg, wh, bh, Vx, G, Hh);
    smsm_k<<<MM, 128, 0, stream>>>(Hh, G, A2);

    t1_k<<<(MM * 384 + 255) / 256, 256, 0, stream>>>(V1, wc1, t1);
    c1_k<<<(MM * 384 + 255) / 256, 256, 0, stream>>>(A2, t1, bc1, c1);
    t2_k<<<(MM * 256 + 255) / 256, 256, 0, stream>>>(c1, wc2, t2);
    v2_k<<<(MM * 256 + 255) / 256, 256, 0, stream>>>(A2, t2, bc2, V2m);

    final_k<<<1, 256, 0, stream>>>(Xf2, V2m, (float*)d_out);
}

// Round 4
// 567.988 us; speedup vs baseline: 1.1469x; 1.1469x over previous
//
#include <hip/hip_runtime.h>
#include <hip/hip_bf16.h>
#include <math.h>

// ---------- dims ----------
#define BATCH 17
#define T_EX 16
#define H0 383
#define W0 287
#define C1 64
#define H1 95
#define W1 71
#define H1P 47
#define W1P 35
#define C2 192
#define H2P 23
#define W2P 17
#define C3 384
#define C45 256
#define H5P 11
#define W5P 8
#define DD 256
#define MM 88
#define TM 1408

#define HP1 389
#define WP1 292

typedef unsigned short ushort_t;
typedef __attribute__((ext_vector_type(8))) short short8;
typedef __attribute__((ext_vector_type(4))) float f32x4;

__device__ __forceinline__ float lrelu(float v) { return v > 0.f ? v : 0.01f * v; }

__device__ __forceinline__ ushort_t f2bf(float f) {
    unsigned int u = __float_as_uint(f);
    unsigned int r = (u + 0x7fffu + ((u >> 16) & 1u)) >> 16;
    return (ushort_t)r;
}
__device__ __forceinline__ float b2f(ushort_t b) {
    return __uint_as_float(((unsigned int)b) << 16);
}
__device__ __forceinline__ short8 ld16(const ushort_t* p) { return *(const short8*)p; }
// async global -> LDS, 16B per lane; LDS dest = wave-uniform base + lane*16
__device__ __forceinline__ void async_cp16(ushort_t* l, const ushort_t* g) {
    __builtin_amdgcn_global_load_lds(
        (const __attribute__((address_space(1))) void*)g,
        (__attribute__((address_space(3))) void*)l, 16, 0, 0);
}

// ---------- zero fill ----------
__global__ void zfill_k(float4* __restrict__ p, int n4) {
    int idx = blockIdx.x * 256 + threadIdx.x;
    if (idx < n4) p[idx] = (float4){0.f, 0.f, 0.f, 0.f};
}

// ---------- conv1 input prep: fp32 NCHW -> bf16 NHWC padded (C=4, pad 2) ----------
__global__ void prep1_k(const float* __restrict__ search, const float* __restrict__ exemp,
                        ushort_t* __restrict__ out) {
    int idx = blockIdx.x * 256 + threadIdx.x;
    if (idx >= BATCH * H0 * W0) return;
    int ix = idx % W0; int t = idx / W0;
    int iy = t % H0; int b = t / H0;
    const float* src = (b == 0) ? search : exemp + (size_t)(b - 1) * 3 * H0 * W0;
    const int hw = H0 * W0;
    float v0 = src[iy * W0 + ix];
    float v1 = src[hw + iy * W0 + ix];
    float v2 = src[2 * hw + iy * W0 + ix];
    ushort4 o;
    o.x = f2bf(v0); o.y = f2bf(v1); o.z = f2bf(v2); o.w = 0;
    *(ushort4*)&out[(((size_t)b * HP1 + iy + 2) * WP1 + ix + 2) * 4] = o;
}

// ---------- conv weight prep: OIHW fp32 -> bf16 MFMA tiles, K-order (ky,kx,ic) ----------
// OCr: real output channels (oc >= OCr zero-filled -> padded M tiles)
__global__ void wprep_k(const float* __restrict__ w, ushort_t* __restrict__ out,
                        int KH, int KWl, int KWr, int CINl, int CINr,
                        int NKS, int nch, int OCr) {
    int idx = blockIdx.x * 256 + threadIdx.x;
    if (idx >= nch) return;
    int c = idx & 255;
    int rest = idx >> 8;
    int ks = rest % NKS;
    int ocb = rest / NKS;
    int k8 = c >> 6, m = c & 63;
    int oc = ocb * 64 + m;
    int KWC = KWl * CINl;
    ushort_t* o = out + (size_t)idx * 8;
#pragma unroll
    for (int j = 0; j < 8; ++j) {
        int kg = ks * 32 + k8 * 8 + j;
        int ky = kg / KWC; int rem = kg - ky * KWC;
        int kx = rem / CINl; int ic = rem - kx * CINl;
        float v = 0.f;
        if (oc < OCr && ky < KH && kx < KWr && ic < CINr)
            v = w[(((size_t)oc * CINr + ic) * KH + ky) * KWr + kx];
        o[j] = f2bf(v);
    }
}

// ---------- fused gemm weight prep (ws1 | ws2 | wcd), tiled layout ----------
__global__ void wprep_gemm_k(const float* __restrict__ ws1, const float* __restrict__ ws2,
                             const float* __restrict__ wcd, ushort_t* __restrict__ WS1T,
                             ushort_t* __restrict__ WS2T, ushort_t* __restrict__ WCDT) {
    int idx = blockIdx.x * 256 + threadIdx.x;
    const float* src; ushort_t* dst; int NKS, mode = 0, sa = 1, sk = 0, base;
    if (idx < 16384)       { src = ws1; dst = WS1T; NKS = 8;  sk = 512; base = idx; }
    else if (idx < 32768)  { src = ws2; dst = WS2T; NKS = 16; sk = 256; base = idx - 16384; }
    else if (idx < 57344)  { src = wcd; dst = WCDT; NKS = 24; mode = 1; base = idx - 32768; }
    else return;
    int c = base & 255;
    int rest = base >> 8;
    int ks = rest % NKS;
    int ocb = rest / NKS;
    int k8 = c >> 6, m = c & 63;
    int oc = ocb * 64 + m;
    ushort_t* o = dst + (size_t)base * 8;
#pragma unroll
    for (int j = 0; j < 8; ++j) {
        int kg = ks * 32 + k8 * 8 + j;
        float v;
        if (mode == 0) v = src[(size_t)oc * sa + (size_t)kg * sk];
        else           v = src[(size_t)oc * 768 + (kg & 255) * 3 + (kg >> 8)];
        o[j] = f2bf(v);
    }
}

// ====================================================================
// bf16 MFMA implicit-GEMM conv, v10: fat 64oc-wide waves.
//  - wave = 64oc x 64px (acc 4x4 f32x4): each 1KB B ds_read feeds 4
//    MFMAs (vs 1 in v5) -> LDS bytes/MFMA drop ~4x; LDS-port cap on
//    MfmaUtil rises ~12% -> ~30-40%.
//  - A (weights) direct from global, pre-tiled MFMA-frag order,
//    L2-resident; ping-pong prefetched in regs (static, unroll-2).
//  - B staged to LDS via global_load_lds DMA, double-buffered, v5's
//    proven full-__syncthreads-per-step schedule (drains DMA+A-loads).
//  - geometry templated: <THREADS, WOC, WPX>: block = WOC*64 oc x
//    WPX*64 px. conv1 <256,1,4>, conv2 <256,2,2> (oc 192 padded to
//    256, masked stores), conv3-5 <64,1,1> (1-wave blocks, cheap
//    intra-wave barriers, max grid parallelism).
//  - each wave stages the px-group it (or its row-peer) computes:
//    stage chunk-group g = wv*GPW + i -> pg = const per wave (static).
// ====================================================================
template <int THREADS, int WOC, int WPX, int STRIDE>
__global__ __launch_bounds__(THREADS, 2) void conv_mfma10(
    const ushort_t* __restrict__ inp, const ushort_t* __restrict__ wt,
    const float* __restrict__ bias, ushort_t* __restrict__ out,
    int Hp, int Wp, int C, int Wout, int HW, int Ntot, int NKS2, int KWl,
    int OHp, int OWp, int OPAD, int COUT) {
    constexpr int NW = THREADS / 64;
    constexpr int GPW = WPX * 8 / NW;        // stage chunk-groups per wave
    static_assert(WOC * WPX == NW, "wave grid");
    const int tid = threadIdx.x;
    const int wv = tid >> 6, lane = tid & 63;
    const int quad = lane >> 4, l16 = lane & 15;
    const int wr = wv / WPX, wc = wv % WPX;
    const int n_blk = blockIdx.x * (WPX * 64);
    const int ocb = blockIdx.y;

    __shared__ ushort_t Bs[2][WPX * 4096];   // [buf][pg][k8:8][px:64][8]
    __shared__ int offs[432];

    const int KWC = KWl * C;
    for (int g = tid; g < NKS2 * 8; g += THREADS) {
        int kg = g * 8;
        int ky = kg / KWC; int rem = kg - ky * KWC;
        int kx = rem / C; int c8 = rem - kx * C;
        offs[g] = (ky * Wp + kx) * C + c8;
    }

    // staging source: this wave stages px-group pg_w, pixel index = lane
    constexpr int PGW_NUM = GPW;             // groups per wave
    const int pg_w = (wv * PGW_NUM) >> 3;    // compile-time-uniform per wave
    const int kq0 = (wv * PGW_NUM) & 7;
    int ns = n_blk + pg_w * 64 + lane; if (ns >= Ntot) ns = Ntot - 1;
    const int bs_ = ns / HW, ps_ = ns - bs_ * HW;
    const int sy = ps_ / Wout, sx = ps_ - sy * Wout;
    const ushort_t* bsrc = inp + (size_t)bs_ * Hp * Wp * C +
                           (size_t)(sy * STRIDE * Wp + sx * STRIDE) * C;

    // A: pre-tiled [oct][ks32][k8:4][m:64][8]; per-thread base
    const int NKS = NKS2 * 2;
    const ushort_t* wA = wt + (size_t)(ocb * WOC + wr) * NKS * 2048 + quad * 512 + l16 * 8;

    f32x4 acc[4][4];
#pragma unroll
    for (int am = 0; am < 4; ++am)
#pragma unroll
        for (int cn = 0; cn < 4; ++cn) acc[am][cn] = (f32x4){0.f, 0.f, 0.f, 0.f};

    __syncthreads();   // offs ready

    auto stage = [&](int buf, int ks) {
        ushort_t* dst = &Bs[buf][wv * (PGW_NUM * 512) + lane * 8];
#pragma unroll
        for (int i = 0; i < PGW_NUM; ++i)
            async_cp16(dst + i * 512, bsrc + offs[ks * 8 + kq0 + i]);
    };
    auto ldA = [&](short8 (&A)[2][4], int ks2) {
        const ushort_t* p = wA + (size_t)ks2 * 4096;
#pragma unroll
        for (int h = 0; h < 2; ++h)
#pragma unroll
            for (int am = 0; am < 4; ++am)
                A[h][am] = ld16(p + h * 2048 + am * 128);
    };
    auto compute = [&](const short8 (&A)[2][4], const ushort_t* Bb) {
#pragma unroll
        for (int h = 0; h < 2; ++h) {
            short8 Bf[4];
#pragma unroll
            for (int cn = 0; cn < 4; ++cn)
                Bf[cn] = *(const short8*)&Bb[wc * 4096 + ((h * 4 + quad) * 64 + cn * 16 + l16) * 8];
#pragma unroll
            for (int cn = 0; cn < 4; ++cn)
#pragma unroll
                for (int am = 0; am < 4; ++am)
                    acc[am][cn] = __builtin_amdgcn_mfma_f32_16x16x32_bf16(A[h][am], Bf[cn], acc[am][cn], 0, 0, 0);
        }
    };

    short8 Aa[2][4], Ab[2][4];
    stage(0, 0);
    ldA(Aa, 0);
    __syncthreads();   // buf0 staged (DMA drained by barrier's vmcnt wait)

    int ks2 = 0;
    for (; ks2 + 2 <= NKS2; ks2 += 2) {
        // even step: Bs[0], Aa; prefetch odd step into Bs[1], Ab
        stage(1, ks2 + 1);
        ldA(Ab, ks2 + 1);
        compute(Aa, &Bs[0][0]);
        __syncthreads();
        // odd step: Bs[1], Ab; prefetch next even step
        if (ks2 + 2 < NKS2) { stage(0, ks2 + 2); ldA(Aa, ks2 + 2); }
        compute(Ab, &Bs[1][0]);
        __syncthreads();
    }
    if (ks2 < NKS2) compute(Aa, &Bs[0][0]);   // odd-NKS2 tail (staged+loaded above)

    const int ocB = (ocb * WOC + wr) * 64;
#pragma unroll
    for (int cn = 0; cn < 4; ++cn) {
        int n = n_blk + wc * 64 + cn * 16 + l16;
        if (n < Ntot) {
            int bb = n / HW; int pix = n - bb * HW;
            int y = pix / Wout, x = pix - y * Wout;
            size_t base = (((size_t)bb * OHp + y + OPAD) * OWp + x + OPAD) * COUT;
#pragma unroll
            for (int am = 0; am < 4; ++am) {
                const int oc = ocB + am * 16 + quad * 4;
                if (oc < COUT) {
                    ushort4 o;
                    o.x = f2bf(fmaxf(acc[am][cn][0] + bias[oc], 0.f));
                    o.y = f2bf(fmaxf(acc[am][cn][1] + bias[oc + 1], 0.f));
                    o.z = f2bf(fmaxf(acc[am][cn][2] + bias[oc + 2], 0.f));
                    o.w = f2bf(fmaxf(acc[am][cn][3] + bias[oc + 3], 0.f));
                    *(ushort4*)&out[base + oc] = o;
                }
            }
        }
    }
}

// ====================================================================
// Generic bf16 MFMA GEMM: A direct from global (tiled), B LDS dbuf.
// ====================================================================
template <int MODE, bool HASBIAS, bool SC1>
__global__ __launch_bounds__(256) void gemm_mfma3(
    const ushort_t* __restrict__ Bsrc, const ushort_t* __restrict__ wt,
    const float* __restrict__ bias, float* __restrict__ out,
    int RS, int N, int NKS, int sn, int sc) {
    const int tid = threadIdx.x;
    const int wv = tid >> 6, lane = tid & 63;
    const int quad = lane >> 4, l16 = lane & 15;
    const int n_blk = blockIdx.x * 64;
    const int ocb = blockIdx.y;

    __shared__ ushort_t Bs[2][2048];

    int n_g = n_blk + lane;
    int n_gc = n_g < N ? n_g : N - 1;
    int row = (MODE == 1) ? (1 + (n_gc & 15)) * MM + (n_gc >> 4) : n_gc;
    const size_t base0 = (size_t)row * RS;

    f32x4 acc[4];
#pragma unroll
    for (int cn = 0; cn < 4; ++cn) acc[cn] = (f32x4){0.f, 0.f, 0.f, 0.f};

    const ushort_t* wblk = wt + (size_t)ocb * NKS * 2048;
    const int afrag = (quad * 64 + wv * 16 + l16) * 8;

    short8 a0 = ld16(wblk + afrag);
    *(short8*)&Bs[0][tid * 8] = ld16(Bsrc + base0 + wv * 8);
    __syncthreads();

    for (int ks = 0; ks < NKS; ++ks) {
        const int cur = ks & 1, nxt = cur ^ 1;
        short8 a1, bn;
        const bool more = (ks + 1 < NKS);
        if (more) {
            a1 = ld16(wblk + (ks + 1) * 2048 + afrag);
            bn = ld16(Bsrc + base0 + (ks + 1) * 32 + wv * 8);
        }
#pragma unroll
        for (int cn = 0; cn < 4; ++cn) {
            const short8 bfr = *(const short8*)&Bs[cur][(quad * 64 + cn * 16 + l16) * 8];
            acc[cn] = __builtin_amdgcn_mfma_f32_16x16x32_bf16(a0, bfr, acc[cn], 0, 0, 0);
        }
        if (more) *(short8*)&Bs[nxt][tid * 8] = bn;
        a0 = a1;
        __syncthreads();
    }

    const int oc0 = ocb * 64 + wv * 16 + quad * 4;
    float bb[4] = {0.f, 0.f, 0.f, 0.f};
    if (HASBIAS) { bb[0] = bias[oc0]; bb[1] = bias[oc0+1]; bb[2] = bias[oc0+2]; bb[3] = bias[oc0+3]; }
#pragma unroll
    for (int cn = 0; cn < 4; ++cn) {
        int n = n_blk + cn * 16 + l16;
        if (n < N) {
            if (SC1) {
                float4 o;
                o.x = acc[cn][0] + bb[0]; o.y = acc[cn][1] + bb[1];
                o.z = acc[cn][2] + bb[2]; o.w = acc[cn][3] + bb[3];
                *(float4*)&out[(size_t)n * sn + oc0] = o;
            } else {
#pragma unroll
                for (int reg = 0; reg < 4; ++reg)
                    out[(size_t)n * sn + (size_t)(oc0 + reg) * sc] = acc[cn][reg] + bb[reg];
            }
        }
    }
}

// ---------- maxpool k3 s2 VALID, NHWC bf16 ----------
__global__ void pool_nhwc(const ushort_t* __restrict__ in, ushort_t* __restrict__ out,
                          int C, int Hin, int Win, int Hout, int Wout,
                          int OHp, int OWp, int OPAD) {
    int total = BATCH * C * Hout * Wout;
    int idx = blockIdx.x * 256 + threadIdx.x;
    if (idx >= total) return;
    int c = idx % C; int r = idx / C;
    int x = r % Wout; r /= Wout;
    int y = r % Hout; int b = r / Hout;
    const int rs = Win * C;
    const ushort_t* p = in + (((size_t)b * Hin + 2 * y) * Win + 2 * x) * C + c;
    float m = b2f(p[0]);
    m = fmaxf(m, b2f(p[C])); m = fmaxf(m, b2f(p[2 * C]));
    m = fmaxf(m, b2f(p[rs])); m = fmaxf(m, b2f(p[rs + C])); m = fmaxf(m, b2f(p[rs + 2 * C]));
    m = fmaxf(m, b2f(p[2 * rs])); m = fmaxf(m, b2f(p[2 * rs + C])); m = fmaxf(m, b2f(p[2 * rs + 2 * C]));
    out[(((size_t)b * OHp + y + OPAD) * OWp + x + OPAD) * C + c] = f2bf(m);
}

// ---------- pool5: NHWC bf16 -> P fp32 [b][m][d] + PB bf16 + XfPad ----------
__global__ void pool5_k(const ushort_t* __restrict__ in, float* __restrict__ P,
                        ushort_t* __restrict__ PB, ushort_t* __restrict__ XfPad) {
    int total = BATCH * 256 * MM;
    int idx = blockIdx.x * 256 + threadIdx.x;
    if (idx >= total) return;
    int c = idx % 256; int r = idx / 256;
    int x = r % W5P; r /= W5P;
    int y = r % H5P; int b = r / H5P;
    const int rs = W2P * 256;
    const ushort_t* p = in + (((size_t)b * H2P + 2 * y) * W2P + 2 * x) * 256 + c;
    float m = b2f(p[0]);
    m = fmaxf(m, b2f(p[256])); m = fmaxf(m, b2f(p[512]));
    m = fmaxf(m, b2f(p[rs])); m = fmaxf(m, b2f(p[rs + 256])); m = fmaxf(m, b2f(p[rs + 512]));
    m = fmaxf(m, b2f(p[2 * rs])); m = fmaxf(m, b2f(p[2 * rs + 256])); m = fmaxf(m, b2f(p[2 * rs + 512]));
    int mm = y * W5P + x;
    size_t o = ((size_t)b * MM + mm) * 256 + c;
    P[o] = m;
    ushort_t mb = f2bf(m);
    PB[o] = mb;
    if (b == 0) XfPad[(size_t)(mm + 1) * 256 + c] = mb;
}

// ---------- v[c] = max_m xc[c*88+m] ----------
__global__ void vmax_k(const float* __restrict__ xc, float* __restrict__ v) {
    int c = blockIdx.x * 64 + threadIdx.x;
    float m = -INFINITY;
    for (int j = 0; j < MM; ++j) m = fmaxf(m, xc[(size_t)c * MM + j]);
    v[c] = m;
}

__global__ void xhat_k(const float* __restrict__ v, const float* __restrict__ wt,
                       const float* __restrict__ bt, float* __restrict__ xhat) {
    __shared__ float lv[256];
    for (int j = threadIdx.x; j < 256; j += 256) lv[j] = v[j];
    __syncthreads();
    int idx = blockIdx.x * 256 + threadIdx.x;
    if (idx >= DD * MM) return;
    int k = idx % MM, o = idx / MM;
    float acc = bt[o];
    for (int i = 0; i < 256; ++i) acc = fmaf(lv[i], wt[(i * 256 + o) * MM + k], acc);
    xhat[idx] = acc;
}

__global__ void s1_k(const float* __restrict__ Y1, float* __restrict__ S1) {
    int idx = blockIdx.x * 256 + threadIdx.x;
    if (idx >= T_EX * 512) return;
    int c = idx % 512, t = idx / 512;
    float acc = 0.f;
    for (int m = 0; m < MM; ++m) acc += Y1[(m * T_EX + t) * 512 + c];
    S1[idx] = acc;
}

__global__ void h1_k(const float* __restrict__ Y1, const float* __restrict__ S1,
                     const float* __restrict__ bs1, ushort_t* __restrict__ h1b) {
    int idx = blockIdx.x * 256 + threadIdx.x;
    if (idx >= TM * 512) return;
    int c = idx % 512; int n = idx / 512;
    int t = n % T_EX;
    float val = S1[t * 512 + c] + bs1[c];
    if (t == 0) val -= Y1[idx];
    h1b[idx] = f2bf(lrelu(val));
}

__global__ void s2_k(const float* __restrict__ Y2, float* __restrict__ S2) {
    int idx = blockIdx.x * 256 + threadIdx.x;
    if (idx >= T_EX * 256) return;
    int c = idx % 256, t = idx / 256;
    float acc = 0.f;
    for (int m = 0; m < MM; ++m) acc += Y2[(m * T_EX + t) * 256 + c];
    S2[idx] = acc;
}

__global__ void h2_k(const float* __restrict__ Y2, const float* __restrict__ S2,
                     const float* __restrict__ bs2, float* __restrict__ h2) {
    int idx = blockIdx.x * 256 + threadIdx.x;
    if (idx >= TM * 256) return;
    int c = idx % 256; int n = idx / 256;
    int t = n % T_EX;
    float val = S2[t * 256 + c] + bs2[c];
    if (t == 0) val -= Y2[idx];
    h2[idx] = lrelu(val);
}

__global__ void v1vx_k(const float* __restrict__ h2, const float* __restrict__ xhat,
                       float* __restrict__ V1, float* __restrict__ Vx) {
    int idx = blockIdx.x * 256 + threadIdx.x;
    if (idx >= DD * MM) return;
    int m = idx % MM, d = idx / MM;
    float mx = -INFINITY;
    for (int t = 0; t < T_EX; ++t) mx = fmaxf(mx, h2[(m * T_EX + t) * 256 + d]);
    V1[idx] = mx;
    Vx[idx] = mx + xhat[idx];
}

__global__ void lin88_k(const float* __restrict__ Wg, const float* __restrict__ bg,
                        const float* __restrict__ Wh, const float* __restrict__ bh,
                        const float* __restrict__ Vin, float* __restrict__ Gout,
                        float* __restrict__ Hout) {
    int idx = blockIdx.x * 256 + threadIdx.x;
    if (idx >= DD * MM) return;
    const float* W = blockIdx.y ? Wh : Wg;
    const float* bias = blockIdx.y ? bh : bg;
    float* out = blockIdx.y ? Hout : Gout;
    int m = idx % MM, o = idx / MM;
    const float* wr = W + o * 256;
    float acc = bias[o];
    for (int i = 0; i < 256; ++i) acc = fmaf(wr[i], Vin[i * MM + m], acc);
    out[idx] = acc;
}

// ---------- fused Smat row + softmax ----------
__global__ void smsm_k(const float* __restrict__ Hh, const float* __restrict__ G,
                       float* __restrict__ A2) {
    int j = blockIdx.x;
    int tid = threadIdx.x;   // 128
    __shared__ float row[96];
    __shared__ float red[128];
    for (int i = tid; i < MM; i += 128) {
        float acc = 0.f;
        for (int c = 0; c < 256; ++c) acc = fmaf(Hh[c * MM + j], G[c * MM + i], acc);
        row[i] = acc;
    }
    __syncthreads();
    float val = (tid < MM) ? row[tid] : -INFINITY;
    red[tid] = val; __syncthreads();
    for (int s = 64; s > 0; s >>= 1) {
        if (tid < s) red[tid] = fmaxf(red[tid], red[tid + s]);
        __syncthreads();
    }
    float mx = red[0]; __syncthreads();
    float e = (tid < MM) ? expf(val - mx) : 0.f;
    red[tid] = e; __syncthreads();
    for (int s = 64; s > 0; s >>= 1) {
        if (tid < s) red[tid] += red[tid + s];
        __syncthreads();
    }
    float inv = 1.f / red[0];
    if (tid < MM) A2[j * MM + tid] = e * inv;
}

__global__ void t1_k(const float* __restrict__ V1, const float* __restrict__ wc1,
                     float* __restrict__ t1) {
    int idx = blockIdx.x * 256 + threadIdx.x;
    if (idx >= MM * 384) return;
    int c = idx % 384, m = idx / 384;
    float acc = 0.f;
    for (int d = 0; d < 256; ++d) acc = fmaf(V1[d * MM + m], wc1[d * 384 + c], acc);
    t1[idx] = acc;
}

__global__ void c1_k(const float* __restrict__ A2, const float* __restrict__ t1,
                     const float* __restrict__ bc1, float* __restrict__ c1) {
    int idx = blockIdx.x * 256 + threadIdx.x;
    if (idx >= MM * 384) return;
    int c = idx % 384, j = idx / 384;
    float acc = bc1[c];
    for (int i = 0; i < MM; ++i) acc = fmaf(A2[j * MM + i], t1[i * 384 + c], acc);
    c1[idx] = lrelu(acc);
}

__global__ void t2_k(const float* __restrict__ c1, const float* __restrict__ wc2,
                     float* __restrict__ t2) {
    int idx = blockIdx.x * 256 + threadIdx.x;
    if (idx >= MM * 256) return;
    int c = idx % 256, m = idx / 256;
    const float* cr = c1 + m * 384;
    float acc = 0.f;
    for (int d = 0; d < 384; ++d) acc = fmaf(cr[d], wc2[d * 256 + c], acc);
    t2[idx] = acc;
}

__global__ void v2_k(const float* __restrict__ A2, const float* __restrict__ t2,
                     const float* __restrict__ bc2, float* __restrict__ V2m) {
    int idx = blockIdx.x * 256 + threadIdx.x;
    if (idx >= MM * 256) return;
    int c = idx % 256, j = idx / 256;
    float acc = bc2[c];
    for (int i = 0; i < MM; ++i) acc = fmaf(A2[j * MM + i], t2[i * 256 + c], acc);
    V2m[idx] = lrelu(acc);
}

__global__ void final_k(const float* __restrict__ Xf2, const float* __restrict__ V2m,
                        float* __restrict__ out) {
    __shared__ float red[256];
    float acc = 0.f;
    for (int idx = threadIdx.x; idx < DD * MM; idx += 256)
        acc = fmaf(Xf2[idx], V2m[idx], acc);
    red[threadIdx.x] = acc; __syncthreads();
    for (int s = 128; s > 0; s >>= 1) {
        if (threadIdx.x < s) red[threadIdx.x] += red[threadIdx.x + s];
        __syncthreads();
    }
    if (threadIdx.x == 0) out[0] = red[0];
}

extern "C" void kernel_launch(void* const* d_in, const int* in_sizes, int n_in,
                              void* d_out, int out_size, void* d_ws, size_t ws_size,
                              hipStream_t stream) {
    const float* search = (const float*)d_in[0];
    const float* exemp  = (const float*)d_in[1];
    const float* aw1 = (const float*)d_in[2];  const float* ab1 = (const float*)d_in[3];
    const float* aw2 = (const float*)d_in[4];  const float* ab2 = (const float*)d_in[5];
    const float* aw3 = (const float*)d_in[6];  const float* ab3 = (const float*)d_in[7];
    const float* aw4 = (const float*)d_in[8];  const float* ab4 = (const float*)d_in[9];
    const float* aw5 = (const float*)d_in[10]; const float* ab5 = (const float*)d_in[11];
    const float* wcd = (const float*)d_in[12]; const float* bcd = (const float*)d_in[13];
    const float* wt  = (const float*)d_in[14]; const float* bt  = (const float*)d_in[15];
    const float* ws1 = (const float*)d_in[16]; const float* bs1 = (const float*)d_in[17];
    const float* ws2 = (const float*)d_in[18]; const float* bs2 = (const float*)d_in[19];
    const float* wg  = (const float*)d_in[20]; const float* bg  = (const float*)d_in[21];
    const float* wh  = (const float*)d_in[22]; const float* bh  = (const float*)d_in[23];
    const float* wc1 = (const float*)d_in[24]; const float* bc1 = (const float*)d_in[25];
    const float* wc2 = (const float*)d_in[26]; const float* bc2 = (const float*)d_in[27];

    float* ws = (float*)d_ws;
    float* R1 = ws;
    float* R2 = ws + 3870720;
    float* R3 = ws + 7544832;
    float* Wg = ws + 8628864;

    ushort_t* in1p  = (ushort_t*)R1;
    ushort_t* c1out = (ushort_t*)R2;
    ushort_t* p1out = (ushort_t*)R3;
    ushort_t* c2out = (ushort_t*)R1;
    ushort_t* p2out = (ushort_t*)R2;
    ushort_t* c3out = (ushort_t*)(R2 + 775200);
    ushort_t* c4out = (ushort_t*)R1;
    ushort_t* c5out = (ushort_t*)R3;
    ushort_t* WT    = (ushort_t*)Wg;

    // ---- conv stack (tiled weights; batch-flattened N; fat 64oc waves) ----
    zfill_k<<<(965500 + 255) / 256, 256, 0, stream>>>((float4*)R1, 965500);
    prep1_k<<<(BATCH * H0 * W0 + 255) / 256, 256, 0, stream>>>(search, exemp, in1p);
    wprep_k<<<(4608 + 255) / 256, 256, 0, stream>>>(aw1, WT, 11, 12, 11, 4, 3, 18, 4608, 64);
    conv_mfma10<256, 1, 4, 4><<<dim3(448, 1), 256, 0, stream>>>(
        in1p, WT, ab1, c1out, HP1, WP1, 4, W1, H1 * W1, BATCH * H1 * W1, 9, 12, H1, W1, 0, 64);
    zfill_k<<<(270504 + 255) / 256, 256, 0, stream>>>((float4*)R3, 270504);
    pool_nhwc<<<(BATCH * 64 * H1P * W1P + 255) / 256, 256, 0, stream>>>(
        c1out, p1out, 64, H1, W1, H1P, W1P, 51, 39, 2);
    // conv2: oc padded 192->256 (zero weights), 128oc x 128px blocks
    wprep_k<<<(51200 + 255) / 256, 256, 0, stream>>>(aw2, WT, 5, 5, 5, 64, 64, 50, 51200, 192);
    conv_mfma10<256, 2, 2, 1><<<dim3(219, 2), 256, 0, stream>>>(
        p1out, WT, ab2, c2out, 51, 39, 64, W1P, H1P * W1P, BATCH * H1P * W1P, 25, 5, H1P, W1P, 0, 192);
    zfill_k<<<(581400 + 255) / 256, 256, 0, stream>>>((float4*)R2, 581400);
    pool_nhwc<<<(BATCH * 192 * H2P * W2P + 255) / 256, 256, 0, stream>>>(
        c2out, p2out, 192, H1P, W1P, H2P, W2P, 25, 19, 1);
    wprep_k<<<(82944 + 255) / 256, 256, 0, stream>>>(aw3, WT, 3, 3, 3, 192, 192, 54, 82944, 384);
    conv_mfma10<64, 1, 1, 1><<<dim3(104, 6), 64, 0, stream>>>(
        p2out, WT, ab3, c3out, 25, 19, 192, W2P, H2P * W2P, BATCH * H2P * W2P, 27, 3, 25, 19, 1, 384);
    zfill_k<<<(258400 + 255) / 256, 256, 0, stream>>>((float4*)R1, 258400);
    wprep_k<<<(110592 + 255) / 256, 256, 0, stream>>>(aw4, WT, 3, 3, 3, 384, 384, 108, 110592, 256);
    conv_mfma10<64, 1, 1, 1><<<dim3(104, 4), 64, 0, stream>>>(
        c3out, WT, ab4, c4out, 25, 19, 384, W2P, H2P * W2P, BATCH * H2P * W2P, 54, 3, 25, 19, 1, 256);
    wprep_k<<<(73728 + 255) / 256, 256, 0, stream>>>(aw5, WT, 3, 3, 3, 256, 256, 72, 73728, 256);
    conv_mfma10<64, 1, 1, 1><<<dim3(104, 4), 64, 0, stream>>>(
        c4out, WT, ab5, c5out, 25, 19, 256, W2P, H2P * W2P, BATCH * H2P * W2P, 36, 3, H2P, W2P, 0, 256);

    // ---- tail region layout in R1 ----
    float*    P      = R1 + 2417664;
    ushort_t* PB     = (ushort_t*)(R1 + 2800640);
    ushort_t* XfPad  = (ushort_t*)(R1 + 2992128);   // rows 0 & 89 zeroed by first R1 zfill
    float*    xc     = R1 + 3003648;

    ushort_t* WS1T = (ushort_t*)Wg;
    ushort_t* WS2T = (ushort_t*)(Wg + 65536);
    ushort_t* WCDT = (ushort_t*)(Wg + 131072);
    wprep_gemm_k<<<(57344 + 255) / 256, 256, 0, stream>>>(ws1, ws2, wcd, WS1T, WS2T, WCDT);

    pool5_k<<<(BATCH * 256 * MM + 255) / 256, 256, 0, stream>>>(c5out, P, PB, XfPad);
    float* Xf2 = P;

    float* v_   = R1 + 0;
    float* xhat = R1 + 1024;
    float* Y1   = R1 + 23552;
    float* S1   = R1 + 744448;
    ushort_t* h1b = (ushort_t*)(R1 + 752640);
    float* Y2   = R1 + 1473536;
    float* S2   = R1 + 1833984;
    float* h2   = R1 + 1838080;
    float* V1   = R1 + 2198528;
    float* Vx   = R1 + 2221056;
    float* G    = R1 + 2243584;
    float* Hh   = R1 + 2266112;
    float* A2   = R1 + 2296832;
    float* t1   = R1 + 2305024;
    float* c1   = R1 + 2338816;
    float* t2   = R1 + 2372608;
    float* V2m  = R1 + 2395136;

    gemm_mfma3<0, true, false><<<dim3(2, 4), 256, 0, stream>>>(
        XfPad, WCDT, bcd, xc, 256, MM, 24, 1, MM);
    vmax_k<<<4, 64, 0, stream>>>(xc, v_);
    xhat_k<<<(DD * MM + 255) / 256, 256, 0, stream>>>(v_, wt, bt, xhat);

    gemm_mfma3<1, false, true><<<dim3(22, 8), 256, 0, stream>>>(
        PB, WS1T, nullptr, Y1, 256, TM, 8, 512, 1);
    s1_k<<<(T_EX * 512 + 255) / 256, 256, 0, stream>>>(Y1, S1);
    h1_k<<<(TM * 512 + 255) / 256, 256, 0, stream>>>(Y1, S1, bs1, h1b);
    gemm_mfma3<0, false, true><<<dim3(22, 4), 256, 0, stream>>>(
        h1b, WS2T, nullptr, Y2, 512, TM, 16, 256, 1);
    s2_k<<<(T_EX * 256 + 255) / 256, 256, 0, stream>>>(Y2, S2);
    h2_k<<<(TM * 256 + 255) / 256, 256, 0, stream>>>(Y2, S2, bs2, h2);
    v1vx_k<<<(DD * MM + 255) / 256, 256, 0, stream>>>(h2, xhat, V1, Vx);

    lin88_k<<<dim3((DD * MM + 255) / 256, 2), 256, 0, stream>>>(wg, bg, wh, bh, Vx, G, Hh);
    smsm_k<<<MM, 128, 0, stream>>>(Hh, G, A2);

    t1_k<<<(MM * 384 + 255) / 256, 256, 0, stream>>>(V1, wc1, t1);
    c1_k<<<(MM * 384 + 255) / 256, 256, 0, stream>>>(A2, t1, bc1, c1);
    t2_k<<<(MM * 256 + 255) / 256, 256, 0, stream>>>(c1, wc2, t2);
    v2_k<<<(MM * 256 + 255) / 256, 256, 0, stream>>>(A2, t2, bc2, V2m);

    final_k<<<1, 256, 0, stream>>>(Xf2, V2m, (float*)d_out);
}